// Round 14
// baseline (229.835 us; speedup 1.0000x reference)
//
#include <hip/hip_runtime.h>
#include <math.h>

#define NQ 4
#define NL 2
#define DIM 16          // 2^NQ
#define BATCH 16
#define CH 256
#define HW 16384        // 128*128
#define CHUNK_B 4                     // batches per chunk
#define NCHUNK (BATCH / CHUNK_B)      // 4 chunks
#define SLICES_PER_CHUNK (CHUNK_B * CH)   // 1024

typedef float floatx4 __attribute__((ext_vector_type(4)));

// ---------------- Kernel 1: per-(b,c) mean over H*W (one chunk) -------------
__global__ void pool_kernel(const float* __restrict__ x, float* __restrict__ pooled,
                            int base_bc) {
    const int bc = base_bc + blockIdx.x;
    const floatx4* x4 = (const floatx4*)(x + (size_t)bc * HW);
    const int tid = threadIdx.x;                     // 256 threads
    float s = 0.f;
#pragma unroll
    for (int k = 0; k < 16; ++k) {                   // 16 float4 / thread
        floatx4 v = x4[tid + k * 256];
        s += v.x + v.y + v.z + v.w;
    }
#pragma unroll
    for (int off = 32; off > 0; off >>= 1) s += __shfl_down(s, off, 64);
    __shared__ float partial[4];
    if ((tid & 63) == 0) partial[tid >> 6] = s;
    __syncthreads();
    if (tid == 0)
        pooled[bc] = (partial[0] + partial[1] + partial[2] + partial[3]) * (1.0f / HW);
}

// ---------------- Kernel 2: gate, one block per batch (chunk of 4) ----------
__global__ void gate_kernel16(const float* __restrict__ pooled,
                              const float* __restrict__ enc_w,  // [NQ, CH]
                              const float* __restrict__ enc_b,  // [NQ]
                              const float* __restrict__ qw,     // [NL, NQ, 3]
                              const float* __restrict__ proj_w, // [CH, NQ]
                              const float* __restrict__ proj_b, // [CH]
                              float* __restrict__ gates1p,
                              int base_b) {
    const int b = base_b + blockIdx.x;     // batch
    const int tid = threadIdx.x;           // 256 threads = 4 waves

    __shared__ float sz[NQ];
    __shared__ float sevs[NQ];

    // z[q] = tanh(dot(pooled[b,:], enc_w[q,:]) + enc_b[q]); wave q does qubit q
    {
        const int q = tid >> 6, lane = tid & 63;
        const float* prow = pooled + b * CH;
        float acc = 0.f;
#pragma unroll
        for (int j = 0; j < 4; ++j) {
            const int c = lane * 4 + j;
            acc += prow[c] * enc_w[q * CH + c];
        }
#pragma unroll
        for (int off = 32; off > 0; off >>= 1) acc += __shfl_down(acc, off, 64);
        if (lane == 0) sz[q] = tanhf(acc + enc_b[q]);
    }
    __syncthreads();

    // 4-qubit statevector on thread 0
    if (tid == 0) {
        float re[DIM], im[DIM];
#pragma unroll
        for (int i = 0; i < DIM; ++i) { re[i] = 0.f; im[i] = 0.f; }
        re[0] = 1.f;

        // AngleEmbedding: RY(z_w) on wire w (wire 0 = MSB)
        for (int w = 0; w < NQ; ++w) {
            const float a = sz[w] * 0.5f;
            const float cc = cosf(a), ss = sinf(a);
            const int m = 1 << (3 - w);
#pragma unroll
            for (int i = 0; i < DIM; ++i) {
                if (i & m) continue;
                const int j = i | m;
                const float r0 = cc * re[i] - ss * re[j];
                const float i0 = cc * im[i] - ss * im[j];
                const float r1 = ss * re[i] + cc * re[j];
                const float i1 = ss * im[i] + cc * im[j];
                re[i] = r0; im[i] = i0; re[j] = r1; im[j] = i1;
            }
        }
        // StronglyEntanglingLayers
        for (int l = 0; l < NL; ++l) {
            for (int w = 0; w < NQ; ++w) {
                const float phi = qw[(l * NQ + w) * 3 + 0];
                const float th  = qw[(l * NQ + w) * 3 + 1];
                const float om  = qw[(l * NQ + w) * 3 + 2];
                const float ct = cosf(0.5f * th), st = sinf(0.5f * th);
                const float am = -0.5f * (phi + om);
                const float ad =  0.5f * (phi - om);
                const float emr = cosf(am), emi = sinf(am);
                const float edr = cosf(ad), edi = sinf(ad);
                const float u00r =  emr * ct, u00i =  emi * ct;
                const float u01r = -edr * st, u01i = -edi * st;
                const float u10r =  edr * st, u10i = -edi * st;
                const float u11r =  emr * ct, u11i = -emi * ct;
                const int m = 1 << (3 - w);
#pragma unroll
                for (int i = 0; i < DIM; ++i) {
                    if (i & m) continue;
                    const int j = i | m;
                    const float ar = re[i], ai = im[i], br = re[j], bi = im[j];
                    re[i] = u00r * ar - u00i * ai + u01r * br - u01i * bi;
                    im[i] = u00r * ai + u00i * ar + u01r * bi + u01i * br;
                    re[j] = u10r * ar - u10i * ai + u11r * br - u11i * bi;
                    im[j] = u10r * ai + u10i * ar + u11r * bi + u11i * br;
                }
            }
            const int r = (l % (NQ - 1)) + 1;
            for (int w = 0; w < NQ; ++w) {
                const int t = (w + r) % NQ;
                const int cm = 1 << (3 - w);
                const int tm = 1 << (3 - t);
#pragma unroll
                for (int i = 0; i < DIM; ++i) {
                    if ((i & cm) && !(i & tm)) {
                        const int j = i | tm;
                        float tr = re[i]; re[i] = re[j]; re[j] = tr;
                        float ti = im[i]; im[i] = im[j]; im[j] = ti;
                    }
                }
            }
        }
        float p[DIM];
#pragma unroll
        for (int i = 0; i < DIM; ++i) p[i] = re[i] * re[i] + im[i] * im[i];
        for (int w = 0; w < NQ; ++w) {
            const int m = 1 << (3 - w);
            float ev = 0.f;
#pragma unroll
            for (int i = 0; i < DIM; ++i) ev += (i & m) ? -p[i] : p[i];
            sevs[w] = ev;
        }
    }
    __syncthreads();

    // gates1p[b,c] = 1 + sigmoid(refined @ proj_w^T + proj_b); c = tid
    {
        const int c = tid;
        const float acc = sevs[0] * proj_w[c * NQ + 0] + sevs[1] * proj_w[c * NQ + 1] +
                          sevs[2] * proj_w[c * NQ + 2] + sevs[3] * proj_w[c * NQ + 3] +
                          proj_b[c];
        gates1p[b * CH + c] = 1.f + 1.f / (1.f + expf(-acc));
    }
}

// ---------------- Kernel 3: out = x * gates1p[b,c] (one chunk) --------------
// Slice was pool-read ~2 us ago -> L3/L2 hot. 16 independent loads (16-deep
// MLP), block-uniform scalar gate load, nt stores (stream out to HBM without
// evicting the upcoming chunks' x lines).
__global__ void scale_kernel(const float* __restrict__ x,
                             const float* __restrict__ gates1p,
                             float* __restrict__ out,
                             int base_bc) {
    const int slice = base_bc + blockIdx.x;
    const int tid = threadIdx.x;
    const floatx4* x4 = (const floatx4*)(x + (size_t)slice * HW);
    floatx4* o4 = (floatx4*)(out + (size_t)slice * HW);
    const float g = gates1p[slice];                      // scalar (block-uniform)
    floatx4 v[16];
#pragma unroll
    for (int k = 0; k < 16; ++k) v[k] = x4[tid + k * 256];
#pragma unroll
    for (int k = 0; k < 16; ++k) {
        v[k] *= g;
        __builtin_nontemporal_store(v[k], &o4[tid + k * 256]);
    }
}

extern "C" void kernel_launch(void* const* d_in, const int* in_sizes, int n_in,
                              void* d_out, int out_size, void* d_ws, size_t ws_size,
                              hipStream_t stream) {
    const float* x      = (const float*)d_in[0];
    const float* enc_w  = (const float*)d_in[1];
    const float* enc_b  = (const float*)d_in[2];
    const float* qw     = (const float*)d_in[3];
    const float* proj_w = (const float*)d_in[4];
    const float* proj_b = (const float*)d_in[5];
    float* out = (float*)d_out;

    float* pooled  = (float*)d_ws;            // [16*256]
    float* gates1p = pooled + BATCH * CH;     // [16*256]

    // Chunked pipeline: P_k -> G_k -> S_k, k = 0..3. Scale re-reads the 64 MB
    // its pool chunk touched ~2 us earlier (L3-hot) instead of 40-100 us later.
    for (int k = 0; k < NCHUNK; ++k) {
        const int base_bc = k * SLICES_PER_CHUNK;
        const int base_b  = k * CHUNK_B;
        pool_kernel<<<SLICES_PER_CHUNK, 256, 0, stream>>>(x, pooled, base_bc);
        gate_kernel16<<<CHUNK_B, 256, 0, stream>>>(pooled, enc_w, enc_b, qw,
                                                   proj_w, proj_b, gates1p, base_b);
        scale_kernel<<<SLICES_PER_CHUNK, 256, 0, stream>>>(x, gates1p, out, base_bc);
    }
}

// Round 15
// 201.013 us; speedup vs baseline: 1.1434x; 1.1434x over previous
//
#include <hip/hip_runtime.h>
#include <math.h>

#define NQ 4
#define NL 2
#define DIM 16          // 2^NQ
#define BATCH 16
#define CH 256
#define HW 16384        // 128*128

typedef float floatx4 __attribute__((ext_vector_type(4)));

// ---------------- Kernel 1: per-(b,c) mean over H*W ----------------
// Plain loads (NOT nontemporal): pool's pass leaves x in L3; serves ~half of
// the scale re-read (R11: nt loads here cost +19 us).
__global__ void pool_kernel(const float* __restrict__ x, float* __restrict__ pooled) {
    const int bc = blockIdx.x;                       // 0..4095
    const floatx4* x4 = (const floatx4*)(x + (size_t)bc * HW);
    const int tid = threadIdx.x;                     // 256 threads
    float s = 0.f;
#pragma unroll
    for (int k = 0; k < 16; ++k) {                   // 16 float4 / thread
        floatx4 v = x4[tid + k * 256];
        s += v.x + v.y + v.z + v.w;
    }
#pragma unroll
    for (int off = 32; off > 0; off >>= 1) s += __shfl_down(s, off, 64);
    __shared__ float partial[4];
    if ((tid & 63) == 0) partial[tid >> 6] = s;
    __syncthreads();
    if (tid == 0)
        pooled[bc] = (partial[0] + partial[1] + partial[2] + partial[3]) * (1.0f / HW);
}

// ------- Kernel 2: fused gate+scale, one block per (b,c) slice --------------
// R13 scale geometry (reverse order, 16-deep MLP, block-uniform gate, nt
// stores) + redundant per-block gate computed WHILE the 16 x-loads are in
// flight (loads issued first; gate latency hides under HBM latency). Deletes
// the separate gate kernel and one launch boundary (~4-6 us, R14 evidence).
// pool->here ordering is free via stream order; no fences/atomics (R10 lesson).
__global__ void scale_gate_kernel(
    const float* __restrict__ x,
    const float* __restrict__ enc_w,   // [NQ, CH]
    const float* __restrict__ enc_b,   // [NQ]
    const float* __restrict__ qw,      // [NL, NQ, 3]
    const float* __restrict__ proj_w,  // [CH, NQ]
    const float* __restrict__ proj_b,  // [CH]
    const float* __restrict__ pooled,  // [BATCH*CH]
    float* __restrict__ out)
{
    const int slice = 4095 - blockIdx.x;   // reverse order (freshest L3 first)
    const int tid = threadIdx.x;
    const int b = slice >> 8;              // batch
    const int c = slice & 255;             // channel

    const floatx4* x4 = (const floatx4*)(x + (size_t)slice * HW);
    floatx4* o4 = (floatx4*)(out + (size_t)slice * HW);

    // ---- issue the 16 independent x loads FIRST (16-deep MLP in flight) ----
    floatx4 v[16];
#pragma unroll
    for (int k = 0; k < 16; ++k) v[k] = x4[tid + k * 256];

    // ---- gate for this slice, computed under the load latency ----
    __shared__ float sz[NQ];
    __shared__ float sevs[NQ];
    __shared__ float sg;

    {   // z[q] = tanh(dot(pooled[b,:], enc_w[q,:]) + enc_b[q]); wave q = qubit q
        const int q = tid >> 6, lane = tid & 63;
        const float* prow = pooled + b * CH;
        float acc = 0.f;
#pragma unroll
        for (int j = 0; j < 4; ++j) {
            const int ch = lane * 4 + j;
            acc += prow[ch] * enc_w[q * CH + ch];
        }
#pragma unroll
        for (int off = 32; off > 0; off >>= 1) acc += __shfl_down(acc, off, 64);
        if (lane == 0) sz[q] = tanhf(acc + enc_b[q]);
    }
    __syncthreads();

    if (tid == 0) {
        float re[DIM], im[DIM];
#pragma unroll
        for (int i = 0; i < DIM; ++i) { re[i] = 0.f; im[i] = 0.f; }
        re[0] = 1.f;

        // AngleEmbedding: RY(z_w) on wire w (wire 0 = MSB)
        for (int w = 0; w < NQ; ++w) {
            const float a = sz[w] * 0.5f;
            const float cc = cosf(a), ss = sinf(a);
            const int m = 1 << (3 - w);
#pragma unroll
            for (int i = 0; i < DIM; ++i) {
                if (i & m) continue;
                const int j = i | m;
                const float r0 = cc * re[i] - ss * re[j];
                const float i0 = cc * im[i] - ss * im[j];
                const float r1 = ss * re[i] + cc * re[j];
                const float i1 = ss * im[i] + cc * im[j];
                re[i] = r0; im[i] = i0; re[j] = r1; im[j] = i1;
            }
        }
        // StronglyEntanglingLayers
        for (int l = 0; l < NL; ++l) {
            for (int w = 0; w < NQ; ++w) {
                const float phi = qw[(l * NQ + w) * 3 + 0];
                const float th  = qw[(l * NQ + w) * 3 + 1];
                const float om  = qw[(l * NQ + w) * 3 + 2];
                const float ct = cosf(0.5f * th), st = sinf(0.5f * th);
                const float am = -0.5f * (phi + om);
                const float ad =  0.5f * (phi - om);
                const float emr = cosf(am), emi = sinf(am);
                const float edr = cosf(ad), edi = sinf(ad);
                const float u00r =  emr * ct, u00i =  emi * ct;
                const float u01r = -edr * st, u01i = -edi * st;
                const float u10r =  edr * st, u10i = -edi * st;
                const float u11r =  emr * ct, u11i = -emi * ct;
                const int m = 1 << (3 - w);
#pragma unroll
                for (int i = 0; i < DIM; ++i) {
                    if (i & m) continue;
                    const int j = i | m;
                    const float ar = re[i], ai = im[i], br = re[j], bi = im[j];
                    re[i] = u00r * ar - u00i * ai + u01r * br - u01i * bi;
                    im[i] = u00r * ai + u00i * ar + u01r * bi + u01i * br;
                    re[j] = u10r * ar - u10i * ai + u11r * br - u11i * bi;
                    im[j] = u10r * ai + u10i * ar + u11r * bi + u11i * br;
                }
            }
            const int r = (l % (NQ - 1)) + 1;
            for (int w = 0; w < NQ; ++w) {
                const int t = (w + r) % NQ;
                const int cm = 1 << (3 - w);
                const int tm = 1 << (3 - t);
#pragma unroll
                for (int i = 0; i < DIM; ++i) {
                    if ((i & cm) && !(i & tm)) {
                        const int j = i | tm;
                        float tr = re[i]; re[i] = re[j]; re[j] = tr;
                        float ti = im[i]; im[i] = im[j]; im[j] = ti;
                    }
                }
            }
        }
        float p[DIM];
#pragma unroll
        for (int i = 0; i < DIM; ++i) p[i] = re[i] * re[i] + im[i] * im[i];
        float evs[NQ];
        for (int w = 0; w < NQ; ++w) {
            const int m = 1 << (3 - w);
            float ev = 0.f;
#pragma unroll
            for (int i = 0; i < DIM; ++i) ev += (i & m) ? -p[i] : p[i];
            evs[w] = ev;
        }
        // this block's single gate (channel c)
        const float acc = evs[0] * proj_w[c * NQ + 0] + evs[1] * proj_w[c * NQ + 1] +
                          evs[2] * proj_w[c * NQ + 2] + evs[3] * proj_w[c * NQ + 3] +
                          proj_b[c];
        sg = 1.f + 1.f / (1.f + expf(-acc));
    }
    __syncthreads();

    // ---- multiply + nt store (loads long since landed) ----
    const float g = sg;
#pragma unroll
    for (int k = 0; k < 16; ++k) {
        v[k] *= g;
        __builtin_nontemporal_store(v[k], &o4[tid + k * 256]);
    }
}

extern "C" void kernel_launch(void* const* d_in, const int* in_sizes, int n_in,
                              void* d_out, int out_size, void* d_ws, size_t ws_size,
                              hipStream_t stream) {
    const float* x      = (const float*)d_in[0];
    const float* enc_w  = (const float*)d_in[1];
    const float* enc_b  = (const float*)d_in[2];
    const float* qw     = (const float*)d_in[3];
    const float* proj_w = (const float*)d_in[4];
    const float* proj_b = (const float*)d_in[5];
    float* out = (float*)d_out;

    float* pooled = (float*)d_ws;             // [16*256]

    pool_kernel<<<BATCH * CH, 256, 0, stream>>>(x, pooled);
    scale_gate_kernel<<<BATCH * CH, 256, 0, stream>>>(x, enc_w, enc_b, qw,
                                                      proj_w, proj_b, pooled, out);
}

// Round 16
// 144.919 us; speedup vs baseline: 1.5860x; 1.3871x over previous
//
#include <hip/hip_runtime.h>
#include <math.h>

#define NQ 4
#define NL 2
#define DIM 16          // 2^NQ
#define BATCH 16
#define CH 256
#define HW 16384        // 128*128

typedef float floatx4 __attribute__((ext_vector_type(4)));

// ---------------- Kernel 1: per-(b,c) mean over H*W ----------------
// Plain loads (NOT nontemporal): pool's pass leaves x resident in L3, which
// serves ~half of scale_kernel's re-read (R11: nt loads here cost +19 us;
// R15 FETCH=136MB re-confirms the ~50% hit rate).
__global__ void pool_kernel(const float* __restrict__ x, float* __restrict__ pooled) {
    const int bc = blockIdx.x;                       // 0..4095
    const floatx4* x4 = (const floatx4*)(x + (size_t)bc * HW);
    const int tid = threadIdx.x;                     // 256 threads
    float s = 0.f;
#pragma unroll
    for (int k = 0; k < 16; ++k) {                   // 16 float4 / thread
        floatx4 v = x4[tid + k * 256];
        s += v.x + v.y + v.z + v.w;
    }
#pragma unroll
    for (int off = 32; off > 0; off >>= 1) s += __shfl_down(s, off, 64);
    __shared__ float partial[4];
    if ((tid & 63) == 0) partial[tid >> 6] = s;
    __syncthreads();
    if (tid == 0)
        pooled[bc] = (partial[0] + partial[1] + partial[2] + partial[3]) * (1.0f / HW);
}

// ---------------- Kernel 2: gate, one block per batch (16 blocks) ----------
// Wave-per-qubit dot (4 waves x 64-lane shuffle reduce); circuit on thread 0.
// 16 blocks only -> redundant serial tail is cheap (R15: at 4096 blocks the
// same tail costs 60 us).
__global__ void gate_kernel16(const float* __restrict__ pooled,
                              const float* __restrict__ enc_w,  // [NQ, CH]
                              const float* __restrict__ enc_b,  // [NQ]
                              const float* __restrict__ qw,     // [NL, NQ, 3]
                              const float* __restrict__ proj_w, // [CH, NQ]
                              const float* __restrict__ proj_b, // [CH]
                              float* __restrict__ gates1p) {
    const int b = blockIdx.x;              // batch
    const int tid = threadIdx.x;           // 256 threads = 4 waves

    __shared__ float sz[NQ];
    __shared__ float sevs[NQ];

    // z[q] = tanh(dot(pooled[b,:], enc_w[q,:]) + enc_b[q]); wave q does qubit q
    {
        const int q = tid >> 6, lane = tid & 63;
        const float* prow = pooled + b * CH;
        float acc = 0.f;
#pragma unroll
        for (int j = 0; j < 4; ++j) {
            const int c = lane * 4 + j;
            acc += prow[c] * enc_w[q * CH + c];
        }
#pragma unroll
        for (int off = 32; off > 0; off >>= 1) acc += __shfl_down(acc, off, 64);
        if (lane == 0) sz[q] = tanhf(acc + enc_b[q]);
    }
    __syncthreads();

    // 4-qubit statevector on thread 0
    if (tid == 0) {
        float re[DIM], im[DIM];
#pragma unroll
        for (int i = 0; i < DIM; ++i) { re[i] = 0.f; im[i] = 0.f; }
        re[0] = 1.f;

        // AngleEmbedding: RY(z_w) on wire w (wire 0 = MSB)
        for (int w = 0; w < NQ; ++w) {
            const float a = sz[w] * 0.5f;
            const float cc = cosf(a), ss = sinf(a);
            const int m = 1 << (3 - w);
#pragma unroll
            for (int i = 0; i < DIM; ++i) {
                if (i & m) continue;
                const int j = i | m;
                const float r0 = cc * re[i] - ss * re[j];
                const float i0 = cc * im[i] - ss * im[j];
                const float r1 = ss * re[i] + cc * re[j];
                const float i1 = ss * im[i] + cc * im[j];
                re[i] = r0; im[i] = i0; re[j] = r1; im[j] = i1;
            }
        }
        // StronglyEntanglingLayers
        for (int l = 0; l < NL; ++l) {
            for (int w = 0; w < NQ; ++w) {
                const float phi = qw[(l * NQ + w) * 3 + 0];
                const float th  = qw[(l * NQ + w) * 3 + 1];
                const float om  = qw[(l * NQ + w) * 3 + 2];
                const float ct = cosf(0.5f * th), st = sinf(0.5f * th);
                const float am = -0.5f * (phi + om);
                const float ad =  0.5f * (phi - om);
                const float emr = cosf(am), emi = sinf(am);
                const float edr = cosf(ad), edi = sinf(ad);
                const float u00r =  emr * ct, u00i =  emi * ct;
                const float u01r = -edr * st, u01i = -edi * st;
                const float u10r =  edr * st, u10i = -edi * st;
                const float u11r =  emr * ct, u11i = -emi * ct;
                const int m = 1 << (3 - w);
#pragma unroll
                for (int i = 0; i < DIM; ++i) {
                    if (i & m) continue;
                    const int j = i | m;
                    const float ar = re[i], ai = im[i], br = re[j], bi = im[j];
                    re[i] = u00r * ar - u00i * ai + u01r * br - u01i * bi;
                    im[i] = u00r * ai + u00i * ar + u01r * bi + u01i * br;
                    re[j] = u10r * ar - u10i * ai + u11r * br - u11i * bi;
                    im[j] = u10r * ai + u10i * ar + u11r * bi + u11i * br;
                }
            }
            const int r = (l % (NQ - 1)) + 1;
            for (int w = 0; w < NQ; ++w) {
                const int t = (w + r) % NQ;
                const int cm = 1 << (3 - w);
                const int tm = 1 << (3 - t);
#pragma unroll
                for (int i = 0; i < DIM; ++i) {
                    if ((i & cm) && !(i & tm)) {
                        const int j = i | tm;
                        float tr = re[i]; re[i] = re[j]; re[j] = tr;
                        float ti = im[i]; im[i] = im[j]; im[j] = ti;
                    }
                }
            }
        }
        float p[DIM];
#pragma unroll
        for (int i = 0; i < DIM; ++i) p[i] = re[i] * re[i] + im[i] * im[i];
        for (int w = 0; w < NQ; ++w) {
            const int m = 1 << (3 - w);
            float ev = 0.f;
#pragma unroll
            for (int i = 0; i < DIM; ++i) ev += (i & m) ? -p[i] : p[i];
            sevs[w] = ev;
        }
    }
    __syncthreads();

    // gates1p[b,c] = 1 + sigmoid(refined @ proj_w^T + proj_b); c = tid
    {
        const int c = tid;
        const float acc = sevs[0] * proj_w[c * NQ + 0] + sevs[1] * proj_w[c * NQ + 1] +
                          sevs[2] * proj_w[c * NQ + 2] + sevs[3] * proj_w[c * NQ + 3] +
                          proj_b[c];
        gates1p[b * CH + c] = 1.f + 1.f / (1.f + expf(-acc));
    }
}

// ---------------- Kernel 3: out = x * gates1p[b,c] ----------------
// One block per (b,c) slice (4096 blocks), reverse order (freshest L3 lines
// first). 16 independent loads issued before any store (16-deep MLP), g is a
// block-uniform scalar load, nt stores keep out from evicting x.
__global__ void scale_kernel(const float* __restrict__ x,
                             const float* __restrict__ gates1p,
                             float* __restrict__ out) {
    const int slice = 4095 - blockIdx.x;                 // reverse order
    const int tid = threadIdx.x;
    const floatx4* x4 = (const floatx4*)(x + (size_t)slice * HW);
    floatx4* o4 = (floatx4*)(out + (size_t)slice * HW);
    const float g = gates1p[slice];                      // scalar (block-uniform)
    floatx4 v[16];
#pragma unroll
    for (int k = 0; k < 16; ++k) v[k] = x4[tid + k * 256];
#pragma unroll
    for (int k = 0; k < 16; ++k) {
        v[k] *= g;
        __builtin_nontemporal_store(v[k], &o4[tid + k * 256]);
    }
}

extern "C" void kernel_launch(void* const* d_in, const int* in_sizes, int n_in,
                              void* d_out, int out_size, void* d_ws, size_t ws_size,
                              hipStream_t stream) {
    const float* x      = (const float*)d_in[0];
    const float* enc_w  = (const float*)d_in[1];
    const float* enc_b  = (const float*)d_in[2];
    const float* qw     = (const float*)d_in[3];
    const float* proj_w = (const float*)d_in[4];
    const float* proj_b = (const float*)d_in[5];
    float* out = (float*)d_out;

    float* pooled  = (float*)d_ws;            // [16*256]
    float* gates1p = pooled + BATCH * CH;     // [16*256]

    pool_kernel<<<BATCH * CH, 256, 0, stream>>>(x, pooled);
    gate_kernel16<<<BATCH, 256, 0, stream>>>(pooled, enc_w, enc_b, qw,
                                             proj_w, proj_b, gates1p);
    scale_kernel<<<BATCH * CH, 256, 0, stream>>>(x, gates1p, out);
}